// Round 12
// baseline (2813.069 us; speedup 1.0000x reference)
//
#include <hip/hip_runtime.h>
#include <hip/hip_bf16.h>

typedef unsigned short u16;
typedef __attribute__((ext_vector_type(8))) short bf16x8;
typedef __attribute__((ext_vector_type(8))) u16   u16x8;
typedef __attribute__((ext_vector_type(4))) float f32x4;

#define T_STEPS 256
#define BATCH   128
#define INDIM   512
#define HDIM    1024
#define GDIM    4096
#define KTOT    1536

#define OFF_XBF   ((size_t)0)
#define XBF_BYTES ((size_t)T_STEPS * BATCH * INDIM * 2)   // 33554432 (fragment-order)
#define OFF_BM    (OFF_XBF + XBF_BYTES)
#define BM_BYTES  ((size_t)2 * GDIM * KTOT * 2)           // 25165824
#define OFF_BIAS  (OFF_BM + BM_BYTES)
#define BIAS_BYTES ((size_t)2 * GDIM * 4)                 // 32768
#define OFF_CNT   (OFF_BIAS + BIAS_BYTES)
#define OFF_ROLL  (OFF_CNT + 8192)
#define ROLL_BYTES ((size_t)(T_STEPS + 1) * 2 * BATCH * HDIM * 2)  // 134742016
#define WS_NEED   (OFF_ROLL + ROLL_BYTES)

__device__ __forceinline__ u16 f2b(float f) {
  __hip_bfloat16 h = __float2bfloat16(f);
  return *reinterpret_cast<u16*>(&h);
}

// ---------------- prepass: shuffle x (f32) into bf16 MFMA-fragment order ----
__global__ void k_cast_x(const float* __restrict__ x, u16* __restrict__ xs) {
  int i = blockIdx.x * 256 + threadIdx.x;      // one 8-elem fragment per thread
  int t   = i >> 13;                           // 8192 frags per t
  int r13 = i & 8191;
  int row = r13 >> 6;                          // 0..127
  int c0  = (r13 & 63) * 8;                    // 0..504
  int q = row >> 5, rloc = row & 31;
  int mi = rloc >> 4, ar = rloc & 15;
  int kq = c0 >> 7, kr = c0 & 127;
  int ks = kr >> 5, h4 = (kr & 31) >> 3;
  int lane = h4 * 16 + ar;
  const float* src = x + ((size_t)t * BATCH + row) * INDIM + c0;
  f32x4 a = *reinterpret_cast<const f32x4*>(src);
  f32x4 b = *reinterpret_cast<const f32x4*>(src + 4);
  u16x8 u;
  u[0] = f2b(a[0]); u[1] = f2b(a[1]); u[2] = f2b(a[2]); u[3] = f2b(a[3]);
  u[4] = f2b(b[0]); u[5] = f2b(b[1]); u[6] = f2b(b[2]); u[7] = f2b(b[3]);
  size_t dst = ((((((size_t)t * 4 + q) * 4 + kq) * 4 + ks) * 2 + mi) * 64 + lane) * 8;
  *reinterpret_cast<u16x8*>(xs + dst) = u;
}

// ---------------- prepass: build merged weight matrix ----------------
// Bm[dir][jt32][c 0..127][k 0..1535]; c -> G = (c>>5)*1024 + jt32*32 + (c&31)
__global__ void k_build_b(const float* __restrict__ Whh_f, const float* __restrict__ Wih_f,
                          const float* __restrict__ Whh_r, const float* __restrict__ Wih_r,
                          u16* __restrict__ Bm) {
  int blk = blockIdx.x;              // 0..63 = dir*32 + jt32
  int dir = blk >> 5, jt = blk & 31;
  const float* Whh = dir ? Whh_r : Whh_f;
  const float* Wih = dir ? Wih_r : Wih_f;
  u16* dst = Bm + (size_t)blk * 128 * KTOT;
  for (int c = 0; c < 128; c++) {
    int G = (c >> 5) * HDIM + jt * 32 + (c & 31);
    for (int k = threadIdx.x; k < KTOT; k += 256) {
      float v = (k < HDIM) ? Whh[(size_t)G * HDIM + k] : Wih[(size_t)G * INDIM + (k - HDIM)];
      dst[c * KTOT + k] = f2b(v);
    }
  }
}

// ---------------- prepass: init roll slot 0 (FRAGMENT order), bias, flags ----
__global__ void k_init(const float* __restrict__ h0f, const float* __restrict__ h0r,
                       const float* __restrict__ bihf, const float* __restrict__ bhhf,
                       const float* __restrict__ bihr, const float* __restrict__ bhhr,
                       u16* __restrict__ hfrag, float* __restrict__ bias,
                       unsigned* __restrict__ flags) {
  int i = blockIdx.x * 256 + threadIdx.x;
  if (i < 2 * BATCH * HDIM) {
    int dir = i / (BATCH * HDIM);
    int rem = i - dir * BATCH * HDIM;
    int r = rem / HDIM, c = rem - r * HDIM;
    int q = r >> 5, rloc = r & 31;
    int mi = rloc >> 4, ar = rloc & 15;
    int kq = c >> 8, ks = (c >> 5) & 7, h4 = (c & 31) >> 3, e = c & 7;
    const float* h0 = dir ? h0r : h0f;
    size_t off = ((size_t)(dir * 4 + q)) * 32768
               + (((size_t)(kq * 8 + ks) * 2 + mi) * 64 + h4 * 16 + ar) * 8 + e;
    hfrag[off] = f2b(h0[rem]);
  }
  if (i < 2 * GDIM) {
    int dir = i / GDIM, g = i - dir * GDIM;
    bias[i] = dir ? (bihr[g] + bhhr[g]) : (bihf[g] + bhhf[g]);
  }
  if (i < 2048) flags[i] = 0;
}

// ---------------- persistent bidirectional LSTM ----------------
// grid 256 x 512, 1 WG/CU (LDS 151.5KB forces it -> allocator targets 256 VGPR
// so the 192-VGPR weight panel stays RESIDENT; no per-step weight reload).
// Chain = (dir,q) per XCD. WG: M=32 x N=128 x K=1536; 8 waves = 4K x 2N.
// h exchanged in MFMA-fragment order. Per-wave release flags; 1 barrier/step
// (partials double-buffered by step parity).
__global__ __launch_bounds__(512, 2)
__attribute__((amdgpu_waves_per_eu(2, 2)))
void k_lstm(
    const u16* __restrict__ xs, const u16* __restrict__ Bm,
    u16* __restrict__ hfrag,
    const float* __restrict__ bias, unsigned* __restrict__ flags,
    const float* __restrict__ c0f, const float* __restrict__ c0r,
    float* __restrict__ out) {
  __shared__ float ldsP[2 * 4 * 128 * 37];   // 151552B: parity x [kq][col128][37]

  // Invalidate stale L1/L2 lines from a previous graph replay.
  __builtin_amdgcn_fence(__ATOMIC_ACQUIRE, "agent");

  const int wg   = blockIdx.x;
  const int grp  = wg & 7;                     // chain, one per XCD
  const int dir  = grp >> 2, q = grp & 3;
  const int jt32 = wg >> 3;                    // 0..31
  const int tid  = threadIdx.x;
  const int w = tid >> 6, lane = tid & 63;
  const int kq = w >> 1, nh = w & 1;           // 4-way K x 2-way N
  const int h4 = lane >> 4, kk = h4 * 8;
  const int ar = lane & 15;

  // ---- persistent weight fragments (bh 128 + bx 64 VGPR) ----
  const u16* bsrc = Bm + (size_t)(dir * 32 + jt32) * 128 * KTOT;
  bf16x8 bh[8][4], bx[4][4];
#pragma unroll
  for (int ks = 0; ks < 8; ks++)
#pragma unroll
    for (int ni = 0; ni < 4; ni++)
      bh[ks][ni] = *reinterpret_cast<const bf16x8*>(
          bsrc + (size_t)(nh * 64 + ni * 16 + ar) * KTOT + 256 * kq + 32 * ks + kk);
#pragma unroll
  for (int ks = 0; ks < 4; ks++)
#pragma unroll
    for (int ni = 0; ni < 4; ni++)
      bx[ks][ni] = *reinterpret_cast<const bf16x8*>(
          bsrc + (size_t)(nh * 64 + ni * 16 + ar) * KTOT + HDIM + 128 * kq + 32 * ks + kk);

  // ---- gating thread mapping: 1 row x 2 adjacent h-cols (row-grouped) ----
  const int rrow = tid >> 4;            // 0..31 local row (wave w -> rows 4w..4w+3)
  const int jl0  = 2 * (tid & 15);      // 0..30 even
  const int row0 = q * 32 + rrow;       // global batch row
  const int jg0  = jt32 * 32 + jl0;     // global h column (even)
  const float* c0 = dir ? c0r : c0f;
  float2 cc = *reinterpret_cast<const float2*>(c0 + (size_t)row0 * HDIM + jg0);
  float cst0 = cc.x, cst1 = cc.y;
  const float2 b_i = *reinterpret_cast<const float2*>(bias + dir * GDIM + 0 * HDIM + jg0);
  const float2 b_f = *reinterpret_cast<const float2*>(bias + dir * GDIM + 1 * HDIM + jg0);
  const float2 b_g = *reinterpret_cast<const float2*>(bias + dir * GDIM + 2 * HDIM + jg0);
  const float2 b_o = *reinterpret_cast<const float2*>(bias + dir * GDIM + 3 * HDIM + jg0);

  // publish position (fragment order): this thread owns (row0, jg0, jg0+1)
  const int pmi = rrow >> 4, par = rrow & 15;
  const int ph4 = jl0 >> 3, pe = jl0 & 7;
  const size_t poff = (((size_t)(jt32 * 2 + pmi) * 64 + ph4 * 16 + par) * 8 + pe);

  // consumer wave kq polls 64 per-(WG,wave) flags: producers jt32' in [8kq,+8)
  const unsigned* fpw = flags + grp * 256 + kq * 64 + lane;
  // producer wave posts its own flag
  unsigned* mypost = flags + grp * 256 + jt32 * 8 + w;

#pragma unroll 1
  for (int s = 0; s < T_STEPS; s++) {
    const int t = dir ? (T_STEPS - 1 - s) : s;

    // ---- x fragment loads (coalesced 1KB bursts), before the wait ----
    bf16x8 ax[4][2];
    {
      const u16* xb = xs + ((((size_t)t * 4 + q) * 4 + kq) * 4) * 2 * 512;
#pragma unroll
      for (int ks = 0; ks < 4; ks++)
#pragma unroll
        for (int mi = 0; mi < 2; mi++)
          ax[ks][mi] = *reinterpret_cast<const bf16x8*>(
              xb + ((size_t)(ks * 2 + mi) * 64 + lane) * 8);
    }

    // ---- fine-grained wait: 64 producer-wave flags ----
    if (s > 0) {
      while (true) {
        unsigned f = __hip_atomic_load(fpw, __ATOMIC_RELAXED, __HIP_MEMORY_SCOPE_AGENT);
        if (__all((int)(f >= (unsigned)s))) break;
        __builtin_amdgcn_s_sleep(1);
      }
      __builtin_amdgcn_sched_barrier(0);   // keep h loads below the wait
    }

    f32x4 acc[2][4];
#pragma unroll
    for (int mi = 0; mi < 2; mi++)
#pragma unroll
      for (int ni = 0; ni < 4; ni++) acc[mi][ni] = f32x4{0.f, 0.f, 0.f, 0.f};

    // ---- h phase: fragment-order coalesced loads -> VGPR, 2 halves ----
    const u16* hB = hfrag + ((size_t)s * 8 + dir * 4 + q) * 32768;
#pragma unroll
    for (int half = 0; half < 2; half++) {
      bf16x8 ah[4][2];
#pragma unroll
      for (int k2 = 0; k2 < 4; k2++)
#pragma unroll
        for (int mi = 0; mi < 2; mi++) {
          int ks = half * 4 + k2;
          ah[k2][mi] = *reinterpret_cast<const bf16x8*>(
              hB + (((size_t)(kq * 8 + ks) * 2 + mi) * 64 + lane) * 8);
        }
      if (half == 0) {
        // x MFMAs overlap the first h-load flight
#pragma unroll
        for (int ks = 0; ks < 4; ks++)
#pragma unroll
          for (int mi = 0; mi < 2; mi++)
#pragma unroll
            for (int ni = 0; ni < 4; ni++)
              acc[mi][ni] = __builtin_amdgcn_mfma_f32_16x16x32_bf16(ax[ks][mi], bx[ks][ni], acc[mi][ni], 0, 0, 0);
      }
#pragma unroll
      for (int k2 = 0; k2 < 4; k2++)
#pragma unroll
        for (int mi = 0; mi < 2; mi++)
#pragma unroll
          for (int ni = 0; ni < 4; ni++)
            acc[mi][ni] = __builtin_amdgcn_mfma_f32_16x16x32_bf16(
                ah[k2][mi], bh[half * 4 + k2][ni], acc[mi][ni], 0, 0, 0);
    }

    // ---- write per-wave partials into parity buffer ----
    float* pbase = ldsP + (s & 1) * (4 * 128 * 37);
    {
      float* pw = pbase + kq * (128 * 37);
#pragma unroll
      for (int mi = 0; mi < 2; mi++)
#pragma unroll
        for (int ni = 0; ni < 4; ni++) {
          int col = nh * 64 + ni * 16 + ar;
          *reinterpret_cast<f32x4*>(pw + col * 37 + mi * 16 + h4 * 4) = acc[mi][ni];
        }
    }
    __syncthreads();   // the ONE barrier: partials visible; parity guards reuse

    // ---- reduce 4 partials + gating (thread: 1 row, 2 h-cols) ----
    float h0v, h1v;
    {
      float gi0 = b_i.x, gi1 = b_i.y, gf0 = b_f.x, gf1 = b_f.y;
      float gg0 = b_g.x, gg1 = b_g.y, go0 = b_o.x, go1 = b_o.y;
#pragma unroll
      for (int k4 = 0; k4 < 4; k4++) {
        const float* p = pbase + k4 * (128 * 37);
        gi0 += p[(0 * 32 + jl0) * 37 + rrow]; gi1 += p[(0 * 32 + jl0 + 1) * 37 + rrow];
        gf0 += p[(1 * 32 + jl0) * 37 + rrow]; gf1 += p[(1 * 32 + jl0 + 1) * 37 + rrow];
        gg0 += p[(2 * 32 + jl0) * 37 + rrow]; gg1 += p[(2 * 32 + jl0 + 1) * 37 + rrow];
        go0 += p[(3 * 32 + jl0) * 37 + rrow]; go1 += p[(3 * 32 + jl0 + 1) * 37 + rrow];
      }
      float i0 = 1.f / (1.f + __expf(-gi0)), i1 = 1.f / (1.f + __expf(-gi1));
      float f0 = 1.f / (1.f + __expf(-gf0)), f1 = 1.f / (1.f + __expf(-gf1));
      float g0 = tanhf(gg0), g1 = tanhf(gg1);
      float o0 = 1.f / (1.f + __expf(-go0)), o1 = 1.f / (1.f + __expf(-go1));
      cst0 = f0 * cst0 + i0 * g0;
      cst1 = f1 * cst1 + i1 * g1;
      h0v = o0 * tanhf(cst0);
      h1v = o1 * tanhf(cst1);

      // publish h for step s+1 (fragment order, write-through to LLC)
      unsigned hp = (unsigned)f2b(h0v) | ((unsigned)f2b(h1v) << 16);
      u16* hD = hfrag + ((size_t)(s + 1) * 8 + dir * 4 + q) * 32768;
      __hip_atomic_store(reinterpret_cast<unsigned*>(hD + poff),
                         hp, __ATOMIC_RELAXED, __HIP_MEMORY_SCOPE_AGENT);
    }

    // ---- PER-WAVE release: ack own h stores -> post own flag ----
    asm volatile("s_waitcnt vmcnt(0)" ::: "memory");
    if (lane == 0)
      __hip_atomic_store(mypost, (unsigned)(s + 1),
                         __ATOMIC_RELAXED, __HIP_MEMORY_SCOPE_AGENT);

    // ---- y stores AFTER the release (off the critical path) ----
    {
      float2 yv; yv.x = h0v; yv.y = h1v;
      *reinterpret_cast<float2*>(out + ((size_t)t * BATCH + row0) * (2 * HDIM)
                                     + (size_t)dir * HDIM + jg0) = yv;
      if (s == T_STEPS - 1) {
        size_t hid = (size_t)T_STEPS * BATCH * 2 * HDIM;
        size_t base2 = hid + (size_t)dir * 2 * BATCH * HDIM;
        *reinterpret_cast<float2*>(out + base2 + (size_t)row0 * HDIM + jg0) = yv;
        float2 cv; cv.x = cst0; cv.y = cst1;
        *reinterpret_cast<float2*>(out + base2 + (size_t)BATCH * HDIM
                                       + (size_t)row0 * HDIM + jg0) = cv;
      }
    }
  }
}

extern "C" void kernel_launch(void* const* d_in, const int* in_sizes, int n_in,
                              void* d_out, int out_size, void* d_ws, size_t ws_size,
                              hipStream_t stream) {
  const float* x     = (const float*)d_in[0];
  const float* h0f   = (const float*)d_in[1];
  const float* c0f   = (const float*)d_in[2];
  const float* h0r   = (const float*)d_in[3];
  const float* c0r   = (const float*)d_in[4];
  const float* Wih_f = (const float*)d_in[5];
  const float* Whh_f = (const float*)d_in[6];
  const float* bih_f = (const float*)d_in[7];
  const float* bhh_f = (const float*)d_in[8];
  const float* Wih_r = (const float*)d_in[9];
  const float* Whh_r = (const float*)d_in[10];
  const float* bih_r = (const float*)d_in[11];
  const float* bhh_r = (const float*)d_in[12];
  float* out = (float*)d_out;
  char* ws = (char*)d_ws;

  if (ws_size < WS_NEED) return;

  u16* xsf        = (u16*)(ws + OFF_XBF);
  u16* Bm         = (u16*)(ws + OFF_BM);
  float* bias     = (float*)(ws + OFF_BIAS);
  unsigned* flags = (unsigned*)(ws + OFF_CNT);
  u16* hfrag      = (u16*)(ws + OFF_ROLL);

  k_cast_x<<<8192, 256, 0, stream>>>(x, xsf);
  k_build_b<<<64, 256, 0, stream>>>(Whh_f, Wih_f, Whh_r, Wih_r, Bm);
  k_init<<<1024, 256, 0, stream>>>(h0f, h0r, bih_f, bhh_f, bih_r, bhh_r,
                                   hfrag, bias, flags);
  k_lstm<<<256, 512, 0, stream>>>(xsf, Bm, hfrag, bias, flags, c0f, c0r, out);
}

// Round 13
// 2270.268 us; speedup vs baseline: 1.2391x; 1.2391x over previous
//
#include <hip/hip_runtime.h>
#include <hip/hip_bf16.h>

typedef unsigned short u16;
typedef __attribute__((ext_vector_type(8))) short bf16x8;
typedef __attribute__((ext_vector_type(8))) u16   u16x8;
typedef __attribute__((ext_vector_type(4))) float f32x4;

#define T_STEPS 256
#define BATCH   128
#define INDIM   512
#define HDIM    1024
#define GDIM    4096
#define KTOT    1536

#define OFF_XBF   ((size_t)0)
#define XBF_BYTES ((size_t)T_STEPS * BATCH * INDIM * 2)   // 33554432 (fragment-order)
#define OFF_BM    (OFF_XBF + XBF_BYTES)
#define BM_BYTES  ((size_t)2 * GDIM * KTOT * 2)           // 25165824
#define OFF_BIAS  (OFF_BM + BM_BYTES)
#define BIAS_BYTES ((size_t)2 * GDIM * 4)                 // 32768
#define OFF_CNT   (OFF_BIAS + BIAS_BYTES)
#define OFF_ROLL  (OFF_CNT + 8192)
#define ROLL_BYTES ((size_t)(T_STEPS + 1) * 2 * BATCH * HDIM * 2)  // 134742016
#define WS_NEED   (OFF_ROLL + ROLL_BYTES)

// h roll: slot s has 4 blocks [dir][mt] of 65536 elems (64 rows x 1024 cols,
// MFMA-fragment order): elem = (((kq*8+ks)*4+mi)*64 + h4*16+ar)*8 + e
//   <-> h[row = mt*64 + 16*mi + ar][col = 256*kq + 32*ks + 8*h4 + e]

__device__ __forceinline__ u16 f2b(float f) {
  __hip_bfloat16 h = __float2bfloat16(f);
  return *reinterpret_cast<u16*>(&h);
}

// ---------------- prepass: shuffle x (f32) into bf16 MFMA-fragment order ----
// xs block per (t,mt): 32768 elems; elem = (((kq*4+ksx)*4+mi)*64 + h4*16+ar)*8 + e
__global__ void k_cast_x(const float* __restrict__ x, u16* __restrict__ xs) {
  int i = blockIdx.x * 256 + threadIdx.x;      // one 8-elem fragment per thread
  int t   = i >> 13;                           // 8192 frags per t
  int r13 = i & 8191;
  int row = r13 >> 6;                          // 0..127
  int c0  = (r13 & 63) * 8;                    // 0..504
  int mt = row >> 6, rloc = row & 63;
  int mi = rloc >> 4, ar = rloc & 15;
  int kq = c0 >> 7, ksx = (c0 >> 5) & 3, h4 = (c0 & 31) >> 3;
  const float* src = x + ((size_t)t * BATCH + row) * INDIM + c0;
  f32x4 a = *reinterpret_cast<const f32x4*>(src);
  f32x4 b = *reinterpret_cast<const f32x4*>(src + 4);
  u16x8 u;
  u[0] = f2b(a[0]); u[1] = f2b(a[1]); u[2] = f2b(a[2]); u[3] = f2b(a[3]);
  u[4] = f2b(b[0]); u[5] = f2b(b[1]); u[6] = f2b(b[2]); u[7] = f2b(b[3]);
  size_t dst = ((size_t)(t * 2 + mt)) * 32768
             + (((size_t)((kq * 4 + ksx) * 4 + mi)) * 64 + h4 * 16 + ar) * 8;
  *reinterpret_cast<u16x8*>(xs + dst) = u;
}

// ---------------- prepass: build merged weight matrix ----------------
// Bm[dir][jt][c 0..63][k 0..1535]; c -> G = (c>>4)*1024 + jt*16 + (c&15)
__global__ void k_build_b(const float* __restrict__ Whh_f, const float* __restrict__ Wih_f,
                          const float* __restrict__ Whh_r, const float* __restrict__ Wih_r,
                          u16* __restrict__ Bm) {
  int blk = blockIdx.x;              // 0..127 = dir*64 + jt
  int dir = blk >> 6, jt = blk & 63;
  const float* Whh = dir ? Whh_r : Whh_f;
  const float* Wih = dir ? Wih_r : Wih_f;
  u16* dst = Bm + (size_t)blk * 64 * KTOT;
  for (int c = 0; c < 64; c++) {
    int G = (c >> 4) * HDIM + jt * 16 + (c & 15);
    for (int k = threadIdx.x; k < KTOT; k += 256) {
      float v = (k < HDIM) ? Whh[(size_t)G * HDIM + k] : Wih[(size_t)G * INDIM + (k - HDIM)];
      dst[c * KTOT + k] = f2b(v);
    }
  }
}

// ---------------- prepass: init roll slot 0 (fragment order), bias, flags ----
__global__ void k_init(const float* __restrict__ h0f, const float* __restrict__ h0r,
                       const float* __restrict__ bihf, const float* __restrict__ bhhf,
                       const float* __restrict__ bihr, const float* __restrict__ bhhr,
                       u16* __restrict__ hfrag, float* __restrict__ bias,
                       unsigned* __restrict__ flags) {
  int i = blockIdx.x * 256 + threadIdx.x;
  if (i < 2 * BATCH * HDIM) {
    int dir = i / (BATCH * HDIM);
    int rem = i - dir * BATCH * HDIM;
    int r = rem / HDIM, c = rem - r * HDIM;
    int mt = r >> 6, rloc = r & 63;
    int mi = rloc >> 4, ar = rloc & 15;
    int kq = c >> 8, ks = (c >> 5) & 7, h4 = (c & 31) >> 3, e = c & 7;
    const float* h0 = dir ? h0r : h0f;
    size_t off = ((size_t)(dir * 2 + mt)) * 65536
               + (((size_t)((kq * 8 + ks) * 4 + mi)) * 64 + h4 * 16 + ar) * 8 + e;
    hfrag[off] = f2b(h0[rem]);
  }
  if (i < 2 * GDIM) {
    int dir = i / GDIM, g = i - dir * GDIM;
    bias[i] = dir ? (bihr[g] + bhhr[g]) : (bihf[g] + bhhf[g]);
  }
  if (i < 512) flags[i] = 0;
}

// ---------------- persistent bidirectional LSTM ----------------
// grid 256 x 512 (1 WG/CU). Chain=(dir,mt) on XCD pair (R4 map). WG: M=64 x
// N=64 x K=1536; 8 waves = 4 K-split x 2 N-split. RESIDENT weights: bh 64 VGPR
// per wave; bx in LDS (64KB, staged once). A-streams fragment-ordered.
// Budget: bh64+acc32+ax64+ah-window64+~35 ~= 250 <= 256 (2 waves/SIMD cap).
__global__ __launch_bounds__(512, 2) void k_lstm(
    const u16* __restrict__ xs, const u16* __restrict__ Bm,
    u16* __restrict__ hfrag,
    const float* __restrict__ bias, unsigned* __restrict__ flags,
    const float* __restrict__ c0f, const float* __restrict__ c0r,
    float* __restrict__ out) {
  __shared__ char ldsAll[70656 + 65536];   // partials [4][64][69] f32 | bx 64KB
  float* ldsP = reinterpret_cast<float*>(ldsAll);
  char* bxl = ldsAll + 70656;

  // Invalidate stale L1/L2 lines from a previous graph replay.
  __builtin_amdgcn_fence(__ATOMIC_ACQUIRE, "agent");

  const int wg   = blockIdx.x;
  const int xcd  = wg & 7, local = wg >> 3;    // round-robin XCD dispatch
  const int grp  = xcd >> 1;                   // 0..3 = (dir,mt) chain
  const int dir  = grp >> 1, mt = grp & 1;
  const int jt   = ((xcd & 1) << 5) | local;   // 0..63
  const int tid  = threadIdx.x;
  const int w = tid >> 6, lane = tid & 63;
  const int kq = w >> 1, nh = w & 1;           // 4-way K x 2-way N
  const int h4 = lane >> 4, kk = h4 * 8;
  const int ar = lane & 15;

  // ---- resident h-part weights: 16 frags = 64 VGPR ----
  const u16* bsrc = Bm + (size_t)(dir * 64 + jt) * 64 * KTOT;
  bf16x8 bh[8][2];
#pragma unroll
  for (int ks = 0; ks < 8; ks++)
#pragma unroll
    for (int ni = 0; ni < 2; ni++)
      bh[ks][ni] = *reinterpret_cast<const bf16x8*>(
          bsrc + (size_t)(nh * 32 + ni * 16 + ar) * KTOT + 256 * kq + 32 * ks + kk);

  // ---- stage x-part weights into LDS (once), fragment layout ----
#pragma unroll
  for (int i = 0; i < 8; i++) {
    int fid = i * 8 + w;                       // 0..63
    int kq2 = fid >> 4, ksx2 = (fid >> 2) & 3, nh2 = (fid >> 1) & 1, ni2 = fid & 1;
    bf16x8 v = *reinterpret_cast<const bf16x8*>(
        bsrc + (size_t)(nh2 * 32 + ni2 * 16 + ar) * KTOT + HDIM + 128 * kq2 + 32 * ksx2 + kk);
    *reinterpret_cast<bf16x8*>(bxl + ((size_t)fid * 64 + lane) * 16) = v;
  }

  // ---- gating thread mapping: 1 row x 2 adjacent h-cols ----
  const int rrow = tid >> 3;            // 0..63 local row
  const int jl0  = 2 * (tid & 7);       // 0..14 even
  const int row0 = mt * 64 + rrow;      // global batch row
  const int jg0  = jt * 16 + jl0;       // global h column (even)
  const float* c0 = dir ? c0r : c0f;
  float2 cc = *reinterpret_cast<const float2*>(c0 + (size_t)row0 * HDIM + jg0);
  float cst0 = cc.x, cst1 = cc.y;
  const float2 b_i = *reinterpret_cast<const float2*>(bias + dir * GDIM + 0 * HDIM + jg0);
  const float2 b_f = *reinterpret_cast<const float2*>(bias + dir * GDIM + 1 * HDIM + jg0);
  const float2 b_g = *reinterpret_cast<const float2*>(bias + dir * GDIM + 2 * HDIM + jg0);
  const float2 b_o = *reinterpret_cast<const float2*>(bias + dir * GDIM + 3 * HDIM + jg0);

  // publish position (fragment order): this thread owns (row0, jg0, jg0+1)
  const size_t poff = (((size_t)(((jg0 >> 8) * 8 + ((jg0 >> 5) & 7)) * 4 + (rrow >> 4))) * 64
                       + ((jg0 & 31) >> 3) * 16 + (rrow & 15)) * 8 + (jg0 & 7);

  // wave kq consumes h-cols [256kq,+256) -> producers jt' in [16kq, 16kq+16)
  const unsigned* fpw = flags + grp * 64 + 16 * kq + (lane & 15);

  __syncthreads();   // bx staged

#pragma unroll 1
  for (int s = 0; s < T_STEPS; s++) {
    const int t = dir ? (T_STEPS - 1 - s) : s;

    // ---- x fragment loads (coalesced 1KB bursts), before the wait ----
    bf16x8 ax[4][4];
    {
      const u16* xb = xs + ((size_t)(t * 2 + mt)) * 32768;
#pragma unroll
      for (int ksx = 0; ksx < 4; ksx++)
#pragma unroll
        for (int mi = 0; mi < 4; mi++)
          ax[ksx][mi] = *reinterpret_cast<const bf16x8*>(
              xb + (((size_t)((kq * 4 + ksx) * 4 + mi)) * 64 + lane) * 8);
    }

    // ---- fine-grained wait: this wave's 16 producers ----
    if (s > 0) {
      while (true) {
        unsigned f = __hip_atomic_load(fpw, __ATOMIC_RELAXED, __HIP_MEMORY_SCOPE_AGENT);
        if (__all((int)(f >= (unsigned)s))) break;
        __builtin_amdgcn_s_sleep(1);
      }
      __builtin_amdgcn_sched_barrier(0);   // keep h loads below the wait
    }

    f32x4 acc[4][2];
#pragma unroll
    for (int mi = 0; mi < 4; mi++)
#pragma unroll
      for (int ni = 0; ni < 2; ni++) acc[mi][ni] = f32x4{0.f, 0.f, 0.f, 0.f};

    const u16* hB = hfrag + ((size_t)(s * 4 + dir * 2 + mt)) * 65536;
    bf16x8 ahA[2][4], ahB[2][4];

#define LOADQ(BUF, G)                                                          \
  {                                                                            \
    _Pragma("unroll")                                                          \
    for (int k2 = 0; k2 < 2; k2++)                                             \
      _Pragma("unroll")                                                        \
      for (int mi = 0; mi < 4; mi++)                                           \
        BUF[k2][mi] = *reinterpret_cast<const bf16x8*>(                        \
            hB + (((size_t)((kq * 8 + 2 * (G) + k2) * 4 + mi)) * 64 + lane) * 8); \
  }
#define MFMAQ(BUF, G)                                                          \
  {                                                                            \
    _Pragma("unroll")                                                          \
    for (int k2 = 0; k2 < 2; k2++)                                             \
      _Pragma("unroll")                                                        \
      for (int mi = 0; mi < 4; mi++)                                           \
        _Pragma("unroll")                                                      \
        for (int ni = 0; ni < 2; ni++)                                         \
          acc[mi][ni] = __builtin_amdgcn_mfma_f32_16x16x32_bf16(               \
              BUF[k2][mi], bh[2 * (G) + k2][ni], acc[mi][ni], 0, 0, 0);        \
  }

    LOADQ(ahA, 0);

    // ---- x MFMAs (bx from LDS) overlap the first h-load flight ----
#pragma unroll
    for (int ksx = 0; ksx < 4; ksx++) {
      bf16x8 bxf[2];
#pragma unroll
      for (int ni = 0; ni < 2; ni++)
        bxf[ni] = *reinterpret_cast<const bf16x8*>(
            bxl + (((size_t)(((kq * 4 + ksx) * 2 + nh) * 2 + ni)) * 64 + lane) * 16);
#pragma unroll
      for (int mi = 0; mi < 4; mi++)
#pragma unroll
        for (int ni = 0; ni < 2; ni++)
          acc[mi][ni] = __builtin_amdgcn_mfma_f32_16x16x32_bf16(ax[ksx][mi], bxf[ni], acc[mi][ni], 0, 0, 0);
    }

    LOADQ(ahB, 1); MFMAQ(ahA, 0);
    LOADQ(ahA, 2); MFMAQ(ahB, 1);
    LOADQ(ahB, 3); MFMAQ(ahA, 2);
    MFMAQ(ahB, 3);
#undef LOADQ
#undef MFMAQ

    // ---- write per-wave partials: [kq][col 64][69] f32 (conflict-free) ----
    {
      float* pw = ldsP + kq * (64 * 69);
#pragma unroll
      for (int mi = 0; mi < 4; mi++)
#pragma unroll
        for (int ni = 0; ni < 2; ni++) {
          int col = nh * 32 + ni * 16 + ar;
          *reinterpret_cast<f32x4*>(pw + col * 69 + mi * 16 + h4 * 4) = acc[mi][ni];
        }
    }
    __syncthreads();

    // ---- reduce 4 partials + gating (thread: 1 row, 2 h-cols) ----
    float h0v, h1v;
    {
      float gi0 = b_i.x, gi1 = b_i.y, gf0 = b_f.x, gf1 = b_f.y;
      float gg0 = b_g.x, gg1 = b_g.y, go0 = b_o.x, go1 = b_o.y;
#pragma unroll
      for (int k4 = 0; k4 < 4; k4++) {
        const float* p = ldsP + k4 * (64 * 69);
        gi0 += p[(0 * 16 + jl0) * 69 + rrow]; gi1 += p[(0 * 16 + jl0 + 1) * 69 + rrow];
        gf0 += p[(1 * 16 + jl0) * 69 + rrow]; gf1 += p[(1 * 16 + jl0 + 1) * 69 + rrow];
        gg0 += p[(2 * 16 + jl0) * 69 + rrow]; gg1 += p[(2 * 16 + jl0 + 1) * 69 + rrow];
        go0 += p[(3 * 16 + jl0) * 69 + rrow]; go1 += p[(3 * 16 + jl0 + 1) * 69 + rrow];
      }
      float i0 = 1.f / (1.f + __expf(-gi0)), i1 = 1.f / (1.f + __expf(-gi1));
      float f0 = 1.f / (1.f + __expf(-gf0)), f1 = 1.f / (1.f + __expf(-gf1));
      float g0 = tanhf(gg0), g1 = tanhf(gg1);
      float o0 = 1.f / (1.f + __expf(-go0)), o1 = 1.f / (1.f + __expf(-go1));
      cst0 = f0 * cst0 + i0 * g0;
      cst1 = f1 * cst1 + i1 * g1;
      h0v = o0 * tanhf(cst0);
      h1v = o1 * tanhf(cst1);

      // publish h for step s+1 (fragment order, write-through to LLC)
      unsigned hp = (unsigned)f2b(h0v) | ((unsigned)f2b(h1v) << 16);
      u16* hD = hfrag + ((size_t)((s + 1) * 4 + dir * 2 + mt)) * 65536;
      __hip_atomic_store(reinterpret_cast<unsigned*>(hD + poff),
                         hp, __ATOMIC_RELAXED, __HIP_MEMORY_SCOPE_AGENT);
    }

    // ---- release: ack h stores -> all waves done -> post flag ----
    asm volatile("s_waitcnt vmcnt(0)" ::: "memory");
    __syncthreads();
    if (tid == 0)
      __hip_atomic_store(flags + grp * 64 + jt, (unsigned)(s + 1),
                         __ATOMIC_RELAXED, __HIP_MEMORY_SCOPE_AGENT);

    // ---- y stores AFTER the release (off the critical path) ----
    {
      float2 yv; yv.x = h0v; yv.y = h1v;
      *reinterpret_cast<float2*>(out + ((size_t)t * BATCH + row0) * (2 * HDIM)
                                     + (size_t)dir * HDIM + jg0) = yv;
      if (s == T_STEPS - 1) {
        size_t hid = (size_t)T_STEPS * BATCH * 2 * HDIM;
        size_t base2 = hid + (size_t)dir * 2 * BATCH * HDIM;
        *reinterpret_cast<float2*>(out + base2 + (size_t)row0 * HDIM + jg0) = yv;
        float2 cv; cv.x = cst0; cv.y = cst1;
        *reinterpret_cast<float2*>(out + base2 + (size_t)BATCH * HDIM
                                       + (size_t)row0 * HDIM + jg0) = cv;
      }
    }
  }
}

extern "C" void kernel_launch(void* const* d_in, const int* in_sizes, int n_in,
                              void* d_out, int out_size, void* d_ws, size_t ws_size,
                              hipStream_t stream) {
  const float* x     = (const float*)d_in[0];
  const float* h0f   = (const float*)d_in[1];
  const float* c0f   = (const float*)d_in[2];
  const float* h0r   = (const float*)d_in[3];
  const float* c0r   = (const float*)d_in[4];
  const float* Wih_f = (const float*)d_in[5];
  const float* Whh_f = (const float*)d_in[6];
  const float* bih_f = (const float*)d_in[7];
  const float* bhh_f = (const float*)d_in[8];
  const float* Wih_r = (const float*)d_in[9];
  const float* Whh_r = (const float*)d_in[10];
  const float* bih_r = (const float*)d_in[11];
  const float* bhh_r = (const float*)d_in[12];
  float* out = (float*)d_out;
  char* ws = (char*)d_ws;

  if (ws_size < WS_NEED) return;

  u16* xsf        = (u16*)(ws + OFF_XBF);
  u16* Bm         = (u16*)(ws + OFF_BM);
  float* bias     = (float*)(ws + OFF_BIAS);
  unsigned* flags = (unsigned*)(ws + OFF_CNT);
  u16* hfrag      = (u16*)(ws + OFF_ROLL);

  k_cast_x<<<8192, 256, 0, stream>>>(x, xsf);
  k_build_b<<<128, 256, 0, stream>>>(Whh_f, Wih_f, Whh_r, Wih_r, Bm);
  k_init<<<1024, 256, 0, stream>>>(h0f, h0r, bih_f, bhh_f, bih_r, bhh_r,
                                   hfrag, bias, flags);
  k_lstm<<<256, 512, 0, stream>>>(xsf, Bm, hfrag, bias, flags, c0f, c0r, out);
}